// Round 8
// baseline (1097.672 us; speedup 1.0000x reference)
//
#include <hip/hip_runtime.h>

typedef unsigned short u16;
typedef unsigned int u32;
typedef __attribute__((ext_vector_type(8))) short bf16x8;
typedef __attribute__((ext_vector_type(4))) float f32x4;

__device__ __forceinline__ u16 f2bf(float f) {
  u32 u = __float_as_uint(f);
  u32 r = (u + 0x7FFFu + ((u >> 16) & 1u)) >> 16;  // RTNE
  return (u16)r;
}

// ---------------- prep: U fp32 -> bf16 ----------------
__global__ __launch_bounds__(256) void cvt_bf16(const float* __restrict__ src,
                                                u16* __restrict__ dst, int n4) {
  int g = blockIdx.x * 256 + threadIdx.x;
  if (g < n4) {
    float4 v = ((const float4*)src)[g];
    ushort4 o;
    o.x = f2bf(v.x); o.y = f2bf(v.y); o.z = f2bf(v.z); o.w = f2bf(v.w);
    ((ushort4*)dst)[g] = o;
  }
}

// ---------------- prep: x fp32 -> Xb bf16 [b][l][d] and XT bf16 [b][d][l] ----------------
__global__ __launch_bounds__(256) void prep_x(const float* __restrict__ x,
                                              u16* __restrict__ Xb,
                                              u16* __restrict__ XT) {
  __shared__ u16 t[32][33];
  const int b = blockIdx.z;
  const int l0 = blockIdx.y * 32;
  const int d0 = blockIdx.x * 32;
  const int j = threadIdx.x & 31;
  const int t5 = threadIdx.x >> 5;
#pragma unroll
  for (int r = 0; r < 4; r++) {
    int i = r * 8 + t5;
    float v = x[((size_t)b * 2048 + l0 + i) * 512 + d0 + j];
    u16 h = f2bf(v);
    t[i][j] = h;
    Xb[((size_t)b * 2048 + l0 + i) * 512 + d0 + j] = h;
  }
  __syncthreads();
#pragma unroll
  for (int r = 0; r < 4; r++) {
    int i = r * 8 + t5;
    XT[((size_t)b * 512 + d0 + i) * 2048 + l0 + j] = t[j][i];
  }
}

__global__ __launch_bounds__(256) void zero_f32(float* __restrict__ p, int n) {
  int g = blockIdx.x * 256 + threadIdx.x;
  if (g < n) p[g] = 0.f;
}

// ---------------- register-streaming batched GEMM: C[b] = A[b] @ B[b]^T ----------------
// NO LDS, NO barriers. 128x128 tile, 4 waves 2x2 (64x64/wave, 4x4 of 16x16x32).
// Each wave loads its A/B fragments directly from global (L2/L3-resident) as
// dwordx4; ping-pong register banks at distance ~1.5 K-steps; the compiler
// emits counted vmcnt waits so loads stay in flight under the MFMA clusters.
// K = OUTER * 16 * 32. Inner 16 steps fully unrolled -> immediate offsets.
// EPI=0: out = bf16(exp(acc)) -> u16* stride N; fused rowsum atomicAdd into z
// EPI=2: out = acc / z[row]   -> float* stride N
template <int EPI, int OUTER>
__global__ __launch_bounds__(256)
void gemm_rs(const u16* __restrict__ A, const u16* __restrict__ B,
             void* __restrict__ Cout, float* __restrict__ z,
             int Kstride, int N,
             size_t Ab_str, size_t Bb_str, size_t Cb_str, int gx, int gy) {
  // flatten + XCD-bijective swizzle (nwg % 8 == 0 in all launches)
  const int nwg = gx * gy * gridDim.z;
  const int orig = blockIdx.x + gx * (blockIdx.y + gy * blockIdx.z);
  const int cpx = nwg >> 3;
  const int nid = (orig & 7) * cpx + (orig >> 3);
  const int bxi = nid % gx;
  const int byi = (nid / gx) % gy;
  const int bzi = nid / (gx * gy);
  const int m0 = byi * 128, n0 = bxi * 128;

  const u16* Ab = A + (size_t)bzi * Ab_str;
  const u16* Bb = B + (size_t)bzi * Bb_str;
  float* zb = z + (size_t)bzi * 8192;

  const int tid = threadIdx.x;
  const int l = tid & 63;
  const int w = tid >> 6;              // wave 0..3
  const int wy = w >> 1, wx = w & 1;   // 2x2 wave grid, 64x64 per wave

  const int fr = l & 15;               // fragment row
  const int fo = (l >> 4) * 8;         // fragment k offset (elems)

  // per-fragment-row base pointers (lanes l, l+16, l+32, l+48 cover one
  // contiguous 64B line of a row -> coalesced dwordx4)
  const u16* pa[4];
  const u16* pb[4];
#pragma unroll
  for (int m = 0; m < 4; m++)
    pa[m] = Ab + (size_t)(m0 + wy * 64 + m * 16 + fr) * Kstride + fo;
#pragma unroll
  for (int n = 0; n < 4; n++)
    pb[n] = Bb + (size_t)(n0 + wx * 64 + n * 16 + fr) * Kstride + fo;

  bf16x8 af[2][4], bf_[2][4];
  f32x4 acc[4][4] = {};

  // prologue: issue k-steps 0 and 1
#pragma unroll
  for (int m = 0; m < 4; m++) af[0][m] = *(const bf16x8*)(pa[m]);
#pragma unroll
  for (int n = 0; n < 4; n++) bf_[0][n] = *(const bf16x8*)(pb[n]);
#pragma unroll
  for (int m = 0; m < 4; m++) af[1][m] = *(const bf16x8*)(pa[m] + 32);
#pragma unroll
  for (int n = 0; n < 4; n++) bf_[1][n] = *(const bf16x8*)(pb[n] + 32);

  for (int o = 0; o < OUTER; ++o) {
#pragma unroll
    for (int s = 0; s < 16; ++s) {
      const int cu = s & 1;
      // consume bank cu (compiler inserts counted vmcnt for these 8 loads)
#pragma unroll
      for (int m = 0; m < 4; m++)
#pragma unroll
        for (int n = 0; n < 4; n++)
          acc[m][n] = __builtin_amdgcn_mfma_f32_16x16x32_bf16(
              af[cu][m], bf_[cu][n], acc[m][n], 0, 0, 0);
      // reissue bank cu for step s+2 (immediate offset, <= 1088 B).
      // Trailing steps of the last outer iter load dead data (stays within
      // ws: next region follows each operand) - never consumed.
#pragma unroll
      for (int m = 0; m < 4; m++)
        af[cu][m] = *(const bf16x8*)(pa[m] + (s + 2) * 32);
#pragma unroll
      for (int n = 0; n < 4; n++)
        bf_[cu][n] = *(const bf16x8*)(pb[n] + (s + 2) * 32);
    }
    if (o + 1 < OUTER) {
#pragma unroll
      for (int m = 0; m < 4; m++) pa[m] += 16 * 32;
#pragma unroll
      for (int n = 0; n < 4; n++) pb[n] += 16 * 32;
    }
  }

  // ---- epilogue ----
  const int rq = (l >> 4) * 4;  // C/D: col=lane&15, row=(lane>>4)*4+reg
#pragma unroll
  for (int m = 0; m < 4; m++) {
    const int lrow = wy * 64 + m * 16 + rq;    // local row in 128-tile
    const int grow = m0 + lrow;
    float rs[4] = {0.f, 0.f, 0.f, 0.f};
    float rzv[4];
    if (EPI == 2) {
#pragma unroll
      for (int r = 0; r < 4; r++) rzv[r] = 1.f / zb[grow + r];
    }
#pragma unroll
    for (int n = 0; n < 4; n++) {
      const int col = n0 + wx * 64 + n * 16 + fr;
#pragma unroll
      for (int r = 0; r < 4; r++) {
        const float v = acc[m][n][r];
        if (EPI == 0) {
          const float e = __expf(v);
          ((u16*)Cout)[(size_t)bzi * Cb_str + (size_t)(grow + r) * N + col] = f2bf(e);
          rs[r] += e;
        } else {
          ((float*)Cout)[(size_t)bzi * Cb_str + (size_t)(grow + r) * N + col] =
              v * rzv[r];
        }
      }
    }
    if (EPI == 0) {
#pragma unroll
      for (int s = 1; s < 16; s <<= 1)
#pragma unroll
        for (int r = 0; r < 4; r++) rs[r] += __shfl_xor(rs[r], s);
      if (fr == 0) {
#pragma unroll
        for (int r = 0; r < 4; r++) atomicAdd(&zb[grow + r], rs[r]);
      }
    }
  }
}

// B=8, L=2048, D=512, Y=8192
extern "C" void kernel_launch(void* const* d_in, const int* in_sizes, int n_in,
                              void* d_out, int out_size, void* d_ws, size_t ws_size,
                              hipStream_t stream) {
  const float* x = (const float*)d_in[0];   // [8][2048][512]
  const float* U = (const float*)d_in[1];   // [8192][512]
  if (n_in >= 2 && in_sizes[0] == 8192 * 512) {
    x = (const float*)d_in[1];
    U = (const float*)d_in[0];
  }
  float* out = (float*)d_out;               // [8][8192][512]
  char* ws = (char*)d_ws;

  // ws layout (bytes)
  u16* Ub = (u16*)ws;                       // 8 MiB
  u16* Xb = (u16*)(ws + 8388608);           // 16 MiB
  u16* XT = (u16*)(ws + 25165824);          // 16 MiB
  u16* P  = (u16*)(ws + 41943040);          // all-batch: 256 MiB
  const size_t need_all = 41943040ull + 268435456ull + 262144ull;

  cvt_bf16<<<4096, 256, 0, stream>>>(U, Ub, (8192 * 512) / 4);
  prep_x<<<dim3(16, 64, 8), 256, 0, stream>>>(x, Xb, XT);

  if (ws_size >= need_all) {
    float* z = (float*)(ws + 41943040 + 268435456);
    zero_f32<<<256, 256, 0, stream>>>(z, 8 * 8192);
    // P[b] = exp(U @ x_b^T), fused rowsum -> z[b]: M=8192, N=2048, K=512
    gemm_rs<0, 1><<<dim3(16, 64, 8), 256, 0, stream>>>(
        Ub, Xb, P, z, 512, 2048,
        0, (size_t)2048 * 512, (size_t)8192 * 2048, 16, 64);
    // out[b] = (P[b] @ XT_b^T) / z[b]: M=8192, N=512, K=2048
    gemm_rs<2, 4><<<dim3(4, 64, 8), 256, 0, stream>>>(
        P, XT, out, z, 2048, 512,
        (size_t)8192 * 2048, (size_t)512 * 2048, (size_t)8192 * 512, 4, 64);
  } else {
    // fallback: per-batch P (32 MiB)
    float* z = (float*)(ws + 41943040 + 33554432);
    zero_f32<<<256, 256, 0, stream>>>(z, 8 * 8192);
    for (int b = 0; b < 8; b++) {
      gemm_rs<0, 1><<<dim3(16, 64, 1), 256, 0, stream>>>(
          Ub, Xb + (size_t)b * 2048 * 512, P, z + b * 8192, 512, 2048,
          0, 0, 0, 16, 64);
      gemm_rs<2, 4><<<dim3(4, 64, 1), 256, 0, stream>>>(
          P, XT + (size_t)b * 512 * 2048, out + (size_t)b * 8192 * 512,
          z + b * 8192, 2048, 512, 0, 0, 0, 4, 64);
    }
  }
}

// Round 9
// 840.267 us; speedup vs baseline: 1.3063x; 1.3063x over previous
//
#include <hip/hip_runtime.h>

typedef unsigned short u16;
typedef unsigned int u32;
typedef __attribute__((ext_vector_type(8))) short bf16x8;
typedef __attribute__((ext_vector_type(4))) float f32x4;

__device__ __forceinline__ u16 f2bf(float f) {
  u32 u = __float_as_uint(f);
  u32 r = (u + 0x7FFFu + ((u >> 16) & 1u)) >> 16;  // RTNE
  return (u16)r;
}

__device__ __forceinline__ void gl_lds16(const u16* g, u16* l) {
  __builtin_amdgcn_global_load_lds(
      (const __attribute__((address_space(1))) u32*)g,
      (__attribute__((address_space(3))) u32*)l, 16, 0, 0);
}

// ---------------- prep: U fp32 -> bf16 ----------------
__global__ __launch_bounds__(256) void cvt_bf16(const float* __restrict__ src,
                                                u16* __restrict__ dst, int n4) {
  int g = blockIdx.x * 256 + threadIdx.x;
  if (g < n4) {
    float4 v = ((const float4*)src)[g];
    ushort4 o;
    o.x = f2bf(v.x); o.y = f2bf(v.y); o.z = f2bf(v.z); o.w = f2bf(v.w);
    ((ushort4*)dst)[g] = o;
  }
}

// ---------------- prep: x fp32 -> Xb bf16 [b][l][d] and XT bf16 [b][d][l] ----------------
__global__ __launch_bounds__(256) void prep_x(const float* __restrict__ x,
                                              u16* __restrict__ Xb,
                                              u16* __restrict__ XT) {
  __shared__ u16 t[32][33];
  const int b = blockIdx.z;
  const int l0 = blockIdx.y * 32;
  const int d0 = blockIdx.x * 32;
  const int j = threadIdx.x & 31;
  const int t5 = threadIdx.x >> 5;
#pragma unroll
  for (int r = 0; r < 4; r++) {
    int i = r * 8 + t5;
    float v = x[((size_t)b * 2048 + l0 + i) * 512 + d0 + j];
    u16 h = f2bf(v);
    t[i][j] = h;
    Xb[((size_t)b * 2048 + l0 + i) * 512 + d0 + j] = h;
  }
  __syncthreads();
#pragma unroll
  for (int r = 0; r < 4; r++) {
    int i = r * 8 + t5;
    XT[((size_t)b * 512 + d0 + i) * 2048 + l0 + j] = t[j][i];
  }
}

__global__ __launch_bounds__(256) void zero_f32(float* __restrict__ p, int n) {
  int g = blockIdx.x * 256 + threadIdx.x;
  if (g < n) p[g] = 0.f;
}

// ---------------- 128xBN-tile batched GEMM: C[b] = A[b] @ B[b]^T ----------------
// m97-regime: BM=128, BK=64, NW waves of 64x64 (2 x BN/64 grid), single-buffered
// swizzled LDS (byte ^= (row&7)<<4), 2-barrier loop, multi-block/CU for TLP.
// gemm1 uses BN=256/NW=8 (edge amortization for short K); gemm2 BN=128/NW=4.
// EPI=0: out = bf16(exp(acc)) -> u16* stride N; fused rowsum atomicAdd into z
// EPI=2: out = acc / z[row]   -> float* stride N
template <int EPI, int BN, int NW>
__global__ __launch_bounds__(NW * 64, NW == 8 ? 6 : 4)
void gemm_t(const u16* __restrict__ A, const u16* __restrict__ B,
            void* __restrict__ Cout, float* __restrict__ z,
            int Kstride, int nt, int N,
            size_t Ab_str, size_t Bb_str, size_t Cb_str, int gx, int gy) {
  constexpr int NT = NW * 64;        // threads
  constexpr int WXW = BN / 64;       // waves along N
  constexpr int RPC = NT / 8;        // rows per staged chunk
  constexpr int CA = 128 / RPC;      // A chunks
  constexpr int CB = BN / RPC;       // B chunks
  __shared__ u16 lA[128 * 64];       // 16 KiB, swizzled
  __shared__ u16 lB[BN * 64];        // BN*128 B, swizzled
  __shared__ float rz_lds[128];

  // flatten + XCD-bijective swizzle (nwg % 8 == 0 in all launches)
  const int nwg = gx * gy * gridDim.z;
  const int orig = blockIdx.x + gx * (blockIdx.y + gy * blockIdx.z);
  const int cpx = nwg >> 3;
  const int nid = (orig & 7) * cpx + (orig >> 3);
  const int bxi = nid % gx;
  const int byi = (nid / gx) % gy;
  const int bzi = nid / (gx * gy);
  const int m0 = byi * 128, n0 = bxi * BN;

  const u16* Ab = A + (size_t)bzi * Ab_str;
  const u16* Bb = B + (size_t)bzi * Bb_str;
  float* zb = z + (size_t)bzi * 8192;

  const int tid = threadIdx.x;
  const int l = tid & 63;
  const int w = tid >> 6;              // wave 0..NW-1
  const int wy = w / WXW, wx = w % WXW;

  // ---- staging constants (write side; inverse-swizzled global source) ----
  const int rowS = tid >> 3;                                  // 0..RPC-1
  const int cS = ((tid & 7) << 4) ^ ((rowS & 7) << 4);        // src byte col
  const u16* srcA0 = Ab + (size_t)(m0 + rowS) * Kstride + (cS >> 1);
  const u16* srcB0 = Bb + (size_t)(n0 + rowS) * Kstride + (cS >> 1);
  const size_t rsk = (size_t)RPC * Kstride;   // chunk row-skip (elems)

  // ---- read-side constants (swizzled ds_read addresses) ----
  const int fr = l & 15;                       // fragment row (within 16)
  const int X = (fr & 7) << 4;                 // swizzle mask (bytes)
  const int kb = (l >> 4) << 4;                // 0,16,32,48 byte col
  const int swz0 = (kb ^ X) >> 1;              // u16 units, k-slice 0
  const int swz1 = ((64 + kb) ^ X) >> 1;       // k-slice 1
  const int aRow = (wy * 64 + fr) * 64;        // u16 index of row base (m=0)
  const int bRow = (wx * 64 + fr) * 64;

  if (EPI == 2 && tid < 128) rz_lds[tid] = 1.f / zb[m0 + tid];

  f32x4 acc[4][4] = {};

  for (int t = 0; t < nt; ++t) {
#pragma unroll
    for (int j = 0; j < CA; j++)
      gl_lds16(srcA0 + j * rsk + t * 64, &lA[tid * 8 + j * RPC * 64]);
#pragma unroll
    for (int j = 0; j < CB; j++)
      gl_lds16(srcB0 + j * rsk + t * 64, &lB[tid * 8 + j * RPC * 64]);
    __syncthreads();   // drains vmcnt -> tile resident
#pragma unroll
    for (int ks = 0; ks < 2; ks++) {
      const int swz = ks ? swz1 : swz0;
      bf16x8 bfr[4], afr[4];
#pragma unroll
      for (int n = 0; n < 4; n++) bfr[n] = *(const bf16x8*)&lB[bRow + n * 1024 + swz];
#pragma unroll
      for (int m = 0; m < 4; m++) afr[m] = *(const bf16x8*)&lA[aRow + m * 1024 + swz];
#pragma unroll
      for (int m = 0; m < 4; m++)
#pragma unroll
        for (int n = 0; n < 4; n++)
          acc[m][n] = __builtin_amdgcn_mfma_f32_16x16x32_bf16(
              afr[m], bfr[n], acc[m][n], 0, 0, 0);
    }
    __syncthreads();   // reads done before next stage overwrites
  }

  // ---- epilogue ----
  const int rq = (l >> 4) * 4;  // C/D: col=lane&15, row=(lane>>4)*4+reg
#pragma unroll
  for (int m = 0; m < 4; m++) {
    const int lrow = wy * 64 + m * 16 + rq;    // local row in 128-tile
    const int grow = m0 + lrow;
    float rs[4] = {0.f, 0.f, 0.f, 0.f};
#pragma unroll
    for (int n = 0; n < 4; n++) {
      const int col = n0 + wx * 64 + n * 16 + fr;
#pragma unroll
      for (int r = 0; r < 4; r++) {
        const float v = acc[m][n][r];
        if (EPI == 0) {
          const float e = __expf(v);
          ((u16*)Cout)[(size_t)bzi * Cb_str + (size_t)(grow + r) * N + col] = f2bf(e);
          rs[r] += e;
        } else {
          ((float*)Cout)[(size_t)bzi * Cb_str + (size_t)(grow + r) * N + col] =
              v * rz_lds[lrow + r];
        }
      }
    }
    if (EPI == 0) {
#pragma unroll
      for (int s = 1; s < 16; s <<= 1)
#pragma unroll
        for (int r = 0; r < 4; r++) rs[r] += __shfl_xor(rs[r], s);
      if (fr == 0) {
#pragma unroll
        for (int r = 0; r < 4; r++) atomicAdd(&zb[grow + r], rs[r]);
      }
    }
  }
}

// B=8, L=2048, D=512, Y=8192
extern "C" void kernel_launch(void* const* d_in, const int* in_sizes, int n_in,
                              void* d_out, int out_size, void* d_ws, size_t ws_size,
                              hipStream_t stream) {
  const float* x = (const float*)d_in[0];   // [8][2048][512]
  const float* U = (const float*)d_in[1];   // [8192][512]
  if (n_in >= 2 && in_sizes[0] == 8192 * 512) {
    x = (const float*)d_in[1];
    U = (const float*)d_in[0];
  }
  float* out = (float*)d_out;               // [8][8192][512]
  char* ws = (char*)d_ws;

  // ws layout (bytes)
  u16* Ub = (u16*)ws;                       // 8 MiB
  u16* Xb = (u16*)(ws + 8388608);           // 16 MiB
  u16* XT = (u16*)(ws + 25165824);          // 16 MiB
  u16* P  = (u16*)(ws + 41943040);          // all-batch: 256 MiB
  const size_t need_all = 41943040ull + 268435456ull + 262144ull;

  cvt_bf16<<<4096, 256, 0, stream>>>(U, Ub, (8192 * 512) / 4);
  prep_x<<<dim3(16, 64, 8), 256, 0, stream>>>(x, Xb, XT);

  if (ws_size >= need_all) {
    float* z = (float*)(ws + 41943040 + 268435456);
    zero_f32<<<256, 256, 0, stream>>>(z, 8 * 8192);
    // P[b] = exp(U @ x_b^T), fused rowsum -> z[b]: M=8192, N=2048, K=512
    gemm_t<0, 256, 8><<<dim3(8, 64, 8), 512, 0, stream>>>(
        Ub, Xb, P, z, 512, 8, 2048,
        0, (size_t)2048 * 512, (size_t)8192 * 2048, 8, 64);
    // out[b] = (P[b] @ XT_b^T) / z[b]: M=8192, N=512, K=2048
    gemm_t<2, 128, 4><<<dim3(4, 64, 8), 256, 0, stream>>>(
        P, XT, out, z, 2048, 32, 512,
        (size_t)8192 * 2048, (size_t)512 * 2048, (size_t)8192 * 512, 4, 64);
  } else {
    // fallback: per-batch P (32 MiB)
    float* z = (float*)(ws + 41943040 + 33554432);
    zero_f32<<<256, 256, 0, stream>>>(z, 8 * 8192);
    for (int b = 0; b < 8; b++) {
      gemm_t<0, 256, 8><<<dim3(8, 64, 1), 512, 0, stream>>>(
          Ub, Xb + (size_t)b * 2048 * 512, P, z + b * 8192, 512, 8, 2048,
          0, 0, 0, 8, 64);
      gemm_t<2, 128, 4><<<dim3(4, 64, 1), 256, 0, stream>>>(
          P, XT + (size_t)b * 512 * 2048, out + (size_t)b * 8192 * 512,
          z + b * 8192, 2048, 32, 512, 0, 0, 0, 4, 64);
    }
  }
}

// Round 10
// 490.145 us; speedup vs baseline: 2.2395x; 1.7143x over previous
//
#include <hip/hip_runtime.h>

typedef unsigned short u16;
typedef unsigned int u32;
typedef __attribute__((ext_vector_type(8))) short bf16x8;
typedef __attribute__((ext_vector_type(4))) float f32x4;

__device__ __forceinline__ u16 f2bf(float f) {
  u32 u = __float_as_uint(f);
  u32 r = (u + 0x7FFFu + ((u >> 16) & 1u)) >> 16;  // RTNE
  return (u16)r;
}

__device__ __forceinline__ void gl_lds16(const u16* g, u16* l) {
  __builtin_amdgcn_global_load_lds(
      (const __attribute__((address_space(1))) u32*)g,
      (__attribute__((address_space(3))) u32*)l, 16, 0, 0);
}

// ---------------- prep: U fp32 -> bf16 ----------------
__global__ __launch_bounds__(256) void cvt_bf16(const float* __restrict__ src,
                                                u16* __restrict__ dst, int n4) {
  int g = blockIdx.x * 256 + threadIdx.x;
  if (g < n4) {
    float4 v = ((const float4*)src)[g];
    ushort4 o;
    o.x = f2bf(v.x); o.y = f2bf(v.y); o.z = f2bf(v.z); o.w = f2bf(v.w);
    ((ushort4*)dst)[g] = o;
  }
}

// ---------------- prep: x fp32 -> Xb bf16 [b][l][d] and XT bf16 [b][d][l] ----------------
__global__ __launch_bounds__(256) void prep_x(const float* __restrict__ x,
                                              u16* __restrict__ Xb,
                                              u16* __restrict__ XT) {
  __shared__ u16 t[32][33];
  const int b = blockIdx.z;
  const int l0 = blockIdx.y * 32;
  const int d0 = blockIdx.x * 32;
  const int j = threadIdx.x & 31;
  const int t5 = threadIdx.x >> 5;
#pragma unroll
  for (int r = 0; r < 4; r++) {
    int i = r * 8 + t5;
    float v = x[((size_t)b * 2048 + l0 + i) * 512 + d0 + j];
    u16 h = f2bf(v);
    t[i][j] = h;
    Xb[((size_t)b * 2048 + l0 + i) * 512 + d0 + j] = h;
  }
  __syncthreads();
#pragma unroll
  for (int r = 0; r < 4; r++) {
    int i = r * 8 + t5;
    XT[((size_t)b * 512 + d0 + i) * 2048 + l0 + j] = t[j][i];
  }
}

__global__ __launch_bounds__(256) void zero_f32(float* __restrict__ p, int n) {
  int g = blockIdx.x * 256 + threadIdx.x;
  if (g < n) p[g] = 0.f;
}

// ---------------- 128xBN-tile batched GEMM: C[b] = A[b] @ B[b]^T ----------------
// m97-regime: BM=128, BK=64, NW waves of 64x64 (2 x BN/64 grid), single-buffered
// swizzled LDS (byte ^= (row&7)<<4), 2-barrier loop, multi-block/CU for TLP.
// gemm1: BN=256/NW=8, __launch_bounds__(512,4) -> VGPR cap 128 (NO spill; the
//   R9 regression was (512,6) capping at ~85 and spilling acc to scratch),
//   2 blocks/CU, 96 KiB LDS. gemm2: BN=128/NW=4, 4 blocks/CU.
// EPI=0: out = bf16(exp(acc)) -> u16* stride N; fused rowsum atomicAdd into z
// EPI=2: out = acc / z[row]   -> float* stride N
template <int EPI, int BN, int NW>
__global__ __launch_bounds__(NW * 64, 4)
void gemm_t(const u16* __restrict__ A, const u16* __restrict__ B,
            void* __restrict__ Cout, float* __restrict__ z,
            int Kstride, int nt, int N,
            size_t Ab_str, size_t Bb_str, size_t Cb_str, int gx, int gy) {
  constexpr int NT = NW * 64;        // threads
  constexpr int WXW = BN / 64;       // waves along N
  constexpr int RPC = NT / 8;        // rows per staged chunk
  constexpr int CA = 128 / RPC;      // A chunks
  constexpr int CB = BN / RPC;       // B chunks
  __shared__ u16 lA[128 * 64];       // 16 KiB, swizzled
  __shared__ u16 lB[BN * 64];        // BN*128 B, swizzled
  __shared__ float rz_lds[128];

  // flatten + XCD-bijective swizzle (nwg % 8 == 0 in all launches)
  const int nwg = gx * gy * gridDim.z;
  const int orig = blockIdx.x + gx * (blockIdx.y + gy * blockIdx.z);
  const int cpx = nwg >> 3;
  const int nid = (orig & 7) * cpx + (orig >> 3);
  const int bxi = nid % gx;
  const int byi = (nid / gx) % gy;
  const int bzi = nid / (gx * gy);
  const int m0 = byi * 128, n0 = bxi * BN;

  const u16* Ab = A + (size_t)bzi * Ab_str;
  const u16* Bb = B + (size_t)bzi * Bb_str;
  float* zb = z + (size_t)bzi * 8192;

  const int tid = threadIdx.x;
  const int l = tid & 63;
  const int w = tid >> 6;              // wave 0..NW-1
  const int wy = w / WXW, wx = w % WXW;

  // ---- staging constants (write side; inverse-swizzled global source) ----
  const int rowS = tid >> 3;                                  // 0..RPC-1
  const int cS = ((tid & 7) << 4) ^ ((rowS & 7) << 4);        // src byte col
  const u16* srcA0 = Ab + (size_t)(m0 + rowS) * Kstride + (cS >> 1);
  const u16* srcB0 = Bb + (size_t)(n0 + rowS) * Kstride + (cS >> 1);
  const size_t rsk = (size_t)RPC * Kstride;   // chunk row-skip (elems)

  // ---- read-side constants (swizzled ds_read addresses) ----
  const int fr = l & 15;                       // fragment row (within 16)
  const int X = (fr & 7) << 4;                 // swizzle mask (bytes)
  const int kb = (l >> 4) << 4;                // 0,16,32,48 byte col
  const int swz0 = (kb ^ X) >> 1;              // u16 units, k-slice 0
  const int swz1 = ((64 + kb) ^ X) >> 1;       // k-slice 1
  const int aRow = (wy * 64 + fr) * 64;        // u16 index of row base (m=0)
  const int bRow = (wx * 64 + fr) * 64;

  if (EPI == 2 && tid < 128) rz_lds[tid] = 1.f / zb[m0 + tid];

  f32x4 acc[4][4] = {};

  for (int t = 0; t < nt; ++t) {
#pragma unroll
    for (int j = 0; j < CA; j++)
      gl_lds16(srcA0 + j * rsk + t * 64, &lA[tid * 8 + j * RPC * 64]);
#pragma unroll
    for (int j = 0; j < CB; j++)
      gl_lds16(srcB0 + j * rsk + t * 64, &lB[tid * 8 + j * RPC * 64]);
    __syncthreads();   // drains vmcnt -> tile resident
#pragma unroll
    for (int ks = 0; ks < 2; ks++) {
      const int swz = ks ? swz1 : swz0;
      bf16x8 bfr[4], afr[4];
#pragma unroll
      for (int n = 0; n < 4; n++) bfr[n] = *(const bf16x8*)&lB[bRow + n * 1024 + swz];
#pragma unroll
      for (int m = 0; m < 4; m++) afr[m] = *(const bf16x8*)&lA[aRow + m * 1024 + swz];
#pragma unroll
      for (int m = 0; m < 4; m++)
#pragma unroll
        for (int n = 0; n < 4; n++)
          acc[m][n] = __builtin_amdgcn_mfma_f32_16x16x32_bf16(
              afr[m], bfr[n], acc[m][n], 0, 0, 0);
    }
    __syncthreads();   // reads done before next stage overwrites
  }

  // ---- epilogue ----
  const int rq = (l >> 4) * 4;  // C/D: col=lane&15, row=(lane>>4)*4+reg
#pragma unroll
  for (int m = 0; m < 4; m++) {
    const int lrow = wy * 64 + m * 16 + rq;    // local row in 128-tile
    const int grow = m0 + lrow;
    float rs[4] = {0.f, 0.f, 0.f, 0.f};
#pragma unroll
    for (int n = 0; n < 4; n++) {
      const int col = n0 + wx * 64 + n * 16 + fr;
#pragma unroll
      for (int r = 0; r < 4; r++) {
        const float v = acc[m][n][r];
        if (EPI == 0) {
          const float e = __expf(v);
          ((u16*)Cout)[(size_t)bzi * Cb_str + (size_t)(grow + r) * N + col] = f2bf(e);
          rs[r] += e;
        } else {
          ((float*)Cout)[(size_t)bzi * Cb_str + (size_t)(grow + r) * N + col] =
              v * rz_lds[lrow + r];
        }
      }
    }
    if (EPI == 0) {
#pragma unroll
      for (int s = 1; s < 16; s <<= 1)
#pragma unroll
        for (int r = 0; r < 4; r++) rs[r] += __shfl_xor(rs[r], s);
      if (fr == 0) {
#pragma unroll
        for (int r = 0; r < 4; r++) atomicAdd(&zb[grow + r], rs[r]);
      }
    }
  }
}

// B=8, L=2048, D=512, Y=8192
extern "C" void kernel_launch(void* const* d_in, const int* in_sizes, int n_in,
                              void* d_out, int out_size, void* d_ws, size_t ws_size,
                              hipStream_t stream) {
  const float* x = (const float*)d_in[0];   // [8][2048][512]
  const float* U = (const float*)d_in[1];   // [8192][512]
  if (n_in >= 2 && in_sizes[0] == 8192 * 512) {
    x = (const float*)d_in[1];
    U = (const float*)d_in[0];
  }
  float* out = (float*)d_out;               // [8][8192][512]
  char* ws = (char*)d_ws;

  // ws layout (bytes)
  u16* Ub = (u16*)ws;                       // 8 MiB
  u16* Xb = (u16*)(ws + 8388608);           // 16 MiB
  u16* XT = (u16*)(ws + 25165824);          // 16 MiB
  u16* P  = (u16*)(ws + 41943040);          // all-batch: 256 MiB
  const size_t need_all = 41943040ull + 268435456ull + 262144ull;

  cvt_bf16<<<4096, 256, 0, stream>>>(U, Ub, (8192 * 512) / 4);
  prep_x<<<dim3(16, 64, 8), 256, 0, stream>>>(x, Xb, XT);

  if (ws_size >= need_all) {
    float* z = (float*)(ws + 41943040 + 268435456);
    zero_f32<<<256, 256, 0, stream>>>(z, 8 * 8192);
    // P[b] = exp(U @ x_b^T), fused rowsum -> z[b]: M=8192, N=2048, K=512
    gemm_t<0, 256, 8><<<dim3(8, 64, 8), 512, 0, stream>>>(
        Ub, Xb, P, z, 512, 8, 2048,
        0, (size_t)2048 * 512, (size_t)8192 * 2048, 8, 64);
    // out[b] = (P[b] @ XT_b^T) / z[b]: M=8192, N=512, K=2048
    gemm_t<2, 128, 4><<<dim3(4, 64, 8), 256, 0, stream>>>(
        P, XT, out, z, 2048, 32, 512,
        (size_t)8192 * 2048, (size_t)512 * 2048, (size_t)8192 * 512, 4, 64);
  } else {
    // fallback: per-batch P (32 MiB)
    float* z = (float*)(ws + 41943040 + 33554432);
    zero_f32<<<256, 256, 0, stream>>>(z, 8 * 8192);
    for (int b = 0; b < 8; b++) {
      gemm_t<0, 256, 8><<<dim3(8, 64, 1), 512, 0, stream>>>(
          Ub, Xb + (size_t)b * 2048 * 512, P, z + b * 8192, 512, 8, 2048,
          0, 0, 0, 8, 64);
      gemm_t<2, 128, 4><<<dim3(4, 64, 1), 256, 0, stream>>>(
          P, XT + (size_t)b * 512 * 2048, out + (size_t)b * 8192 * 512,
          z + b * 8192, 2048, 32, 512, 0, 0, 0, 4, 64);
    }
  }
}

// Round 11
// 473.309 us; speedup vs baseline: 2.3191x; 1.0356x over previous
//
#include <hip/hip_runtime.h>

typedef unsigned short u16;
typedef unsigned int u32;
typedef __attribute__((ext_vector_type(8))) short bf16x8;
typedef __attribute__((ext_vector_type(4))) float f32x4;

__device__ __forceinline__ u16 f2bf(float f) {
  u32 u = __float_as_uint(f);
  u32 r = (u + 0x7FFFu + ((u >> 16) & 1u)) >> 16;  // RTNE
  return (u16)r;
}

__device__ __forceinline__ void gl_lds16(const u16* g, u16* l) {
  __builtin_amdgcn_global_load_lds(
      (const __attribute__((address_space(1))) u32*)g,
      (__attribute__((address_space(3))) u32*)l, 16, 0, 0);
}

// ---------------- prep: U fp32 -> bf16 ----------------
__global__ __launch_bounds__(256) void cvt_bf16(const float* __restrict__ src,
                                                u16* __restrict__ dst, int n4) {
  int g = blockIdx.x * 256 + threadIdx.x;
  if (g < n4) {
    float4 v = ((const float4*)src)[g];
    ushort4 o;
    o.x = f2bf(v.x); o.y = f2bf(v.y); o.z = f2bf(v.z); o.w = f2bf(v.w);
    ((ushort4*)dst)[g] = o;
  }
}

// ---------------- prep: x fp32 -> Xb bf16 [b][l][d] and XT bf16 [b][d][l] ----------------
__global__ __launch_bounds__(256) void prep_x(const float* __restrict__ x,
                                              u16* __restrict__ Xb,
                                              u16* __restrict__ XT) {
  __shared__ u16 t[32][33];
  const int b = blockIdx.z;
  const int l0 = blockIdx.y * 32;
  const int d0 = blockIdx.x * 32;
  const int j = threadIdx.x & 31;
  const int t5 = threadIdx.x >> 5;
#pragma unroll
  for (int r = 0; r < 4; r++) {
    int i = r * 8 + t5;
    float v = x[((size_t)b * 2048 + l0 + i) * 512 + d0 + j];
    u16 h = f2bf(v);
    t[i][j] = h;
    Xb[((size_t)b * 2048 + l0 + i) * 512 + d0 + j] = h;
  }
  __syncthreads();
#pragma unroll
  for (int r = 0; r < 4; r++) {
    int i = r * 8 + t5;
    XT[((size_t)b * 512 + d0 + i) * 2048 + l0 + j] = t[j][i];
  }
}

__global__ __launch_bounds__(256) void zero_f32(float* __restrict__ p, int n) {
  int g = blockIdx.x * 256 + threadIdx.x;
  if (g < n) p[g] = 0.f;
}

// ---------------- gemm1 persistent: P[b] = bf16(exp(U @ x_b^T)), rowsum -> z ----------------
// 128x128 tile, BK=64, 4 waves 2x2, swizzled single-buffer LDS, 2-barrier loop.
// Grid 16x64 = 1024 blocks = 4/CU, ALL resident; each block loops over nb
// batches for its fixed (m0,n0). First tile of batch bz+1 is staged BEFORE
// the epilogue of bz, so staging overlaps exp/store/atomic epilogue work.
// K=512 (nt=8), N=2048 fixed.
__global__ __launch_bounds__(256, 4)
void gemm1p(const u16* __restrict__ A, const u16* __restrict__ B,
            u16* __restrict__ P, float* __restrict__ z,
            int nb, size_t Bb_str, size_t Cb_str, int gx, int gy) {
  __shared__ u16 lA[8192];   // [128 rows][64 k] swizzled, 16 KiB
  __shared__ u16 lB[8192];

  const int nwg = gx * gy;
  const int orig = blockIdx.x + gx * blockIdx.y;
  const int cpx = nwg >> 3;
  const int nid = (orig & 7) * cpx + (orig >> 3);
  const int bxi = nid % gx;
  const int byi = nid / gx;
  const int m0 = byi * 128, n0 = bxi * 128;

  const int tid = threadIdx.x;
  const int l = tid & 63;
  const int w = tid >> 6;
  const int wy = w >> 1, wx = w & 1;

  // staging constants (write side; inverse-swizzled global source)
  const int rowS = tid >> 3;                                  // 0..31
  const int cS = ((tid & 7) << 4) ^ ((rowS & 7) << 4);
  const u16* srcA0 = A + (size_t)(m0 + rowS) * 512 + (cS >> 1);
  const u16* srcB0 = B + (size_t)(n0 + rowS) * 512 + (cS >> 1);  // batch 0
  const size_t rsk = (size_t)32 * 512;

  // read-side constants (swizzled ds_read addresses)
  const int fr = l & 15;
  const int X = (fr & 7) << 4;
  const int kb = (l >> 4) << 4;
  const int swz0 = (kb ^ X) >> 1;
  const int swz1 = ((64 + kb) ^ X) >> 1;
  const int aRow = (wy * 64 + fr) * 64;
  const int bRow = (wx * 64 + fr) * 64;
  const int rq = (l >> 4) * 4;

#define STAGE1(NBZ, NQ)                                                        \
  do {                                                                         \
    _Pragma("unroll") for (int j = 0; j < 4; j++) {                            \
      gl_lds16(srcA0 + j * rsk + (NQ) * 64, &lA[tid * 8 + j * 2048]);          \
      gl_lds16(srcB0 + (size_t)(NBZ) * Bb_str + j * rsk + (NQ) * 64,           \
               &lB[tid * 8 + j * 2048]);                                       \
    }                                                                          \
  } while (0)

  STAGE1(0, 0);  // prologue

  for (int bz = 0; bz < nb; ++bz) {
    f32x4 acc[4][4] = {};
#pragma unroll
    for (int t = 0; t < 8; ++t) {
      __syncthreads();   // staged tile resident (drains vmcnt)
#pragma unroll
      for (int ks = 0; ks < 2; ks++) {
        const int swz = ks ? swz1 : swz0;
        bf16x8 bfr[4], afr[4];
#pragma unroll
        for (int n = 0; n < 4; n++) bfr[n] = *(const bf16x8*)&lB[bRow + n * 1024 + swz];
#pragma unroll
        for (int m = 0; m < 4; m++) afr[m] = *(const bf16x8*)&lA[aRow + m * 1024 + swz];
#pragma unroll
        for (int m = 0; m < 4; m++)
#pragma unroll
          for (int n = 0; n < 4; n++)
            acc[m][n] = __builtin_amdgcn_mfma_f32_16x16x32_bf16(
                afr[m], bfr[n], acc[m][n], 0, 0, 0);
      }
      __syncthreads();   // all waves' reads done -> buffer reusable
      if (t < 7) {
        STAGE1(bz, t + 1);
      } else if (bz + 1 < nb) {
        STAGE1(bz + 1, 0);   // flies under the epilogue below
      }
    }
    // ---- epilogue for batch bz (registers + global only; LDS untouched) ----
    float* zb = z + (size_t)bz * 8192;
    u16* Pb = P + (size_t)bz * Cb_str;
#pragma unroll
    for (int m = 0; m < 4; m++) {
      const int grow = m0 + wy * 64 + m * 16 + rq;
      float rs[4] = {0.f, 0.f, 0.f, 0.f};
#pragma unroll
      for (int n = 0; n < 4; n++) {
        const int col = n0 + wx * 64 + n * 16 + fr;
#pragma unroll
        for (int r = 0; r < 4; r++) {
          const float e = __expf(acc[m][n][r]);
          Pb[(size_t)(grow + r) * 2048 + col] = f2bf(e);
          rs[r] += e;
        }
      }
#pragma unroll
      for (int s = 1; s < 16; s <<= 1)
#pragma unroll
        for (int r = 0; r < 4; r++) rs[r] += __shfl_xor(rs[r], s);
      if (fr == 0) {
#pragma unroll
        for (int r = 0; r < 4; r++) atomicAdd(&zb[grow + r], rs[r]);
      }
    }
  }
#undef STAGE1
}

// ---------------- gemm2 (R7-exact): out[b] = (P[b] @ XT_b^T) / z[b] ----------------
__global__ __launch_bounds__(256, 4)
void gemm2k(const u16* __restrict__ A, const u16* __restrict__ B,
            float* __restrict__ Cout, const float* __restrict__ z,
            int Kstride, int nt, int N,
            size_t Ab_str, size_t Bb_str, size_t Cb_str, int gx, int gy) {
  __shared__ u16 lA[8192];
  __shared__ u16 lB[8192];
  __shared__ float rz_lds[128];

  const int nwg = gx * gy * gridDim.z;
  const int orig = blockIdx.x + gx * (blockIdx.y + gy * blockIdx.z);
  const int cpx = nwg >> 3;
  const int nid = (orig & 7) * cpx + (orig >> 3);
  const int bxi = nid % gx;
  const int byi = (nid / gx) % gy;
  const int bzi = nid / (gx * gy);
  const int m0 = byi * 128, n0 = bxi * 128;

  const u16* Ab = A + (size_t)bzi * Ab_str;
  const u16* Bb = B + (size_t)bzi * Bb_str;

  const int tid = threadIdx.x;
  const int l = tid & 63;
  const int w = tid >> 6;
  const int wy = w >> 1, wx = w & 1;

  const int rowS = tid >> 3;
  const int cS = ((tid & 7) << 4) ^ ((rowS & 7) << 4);
  const u16* srcA0 = Ab + (size_t)(m0 + rowS) * Kstride + (cS >> 1);
  const u16* srcB0 = Bb + (size_t)(n0 + rowS) * Kstride + (cS >> 1);
  const size_t rsk = (size_t)32 * Kstride;

  const int fr = l & 15;
  const int X = (fr & 7) << 4;
  const int kb = (l >> 4) << 4;
  const int swz0 = (kb ^ X) >> 1;
  const int swz1 = ((64 + kb) ^ X) >> 1;
  const int aRow = (wy * 64 + fr) * 64;
  const int bRow = (wx * 64 + fr) * 64;

  if (tid < 128) rz_lds[tid] = 1.f / z[(size_t)bzi * 8192 + m0 + tid];

  f32x4 acc[4][4] = {};

  for (int t = 0; t < nt; ++t) {
#pragma unroll
    for (int j = 0; j < 4; j++) {
      gl_lds16(srcA0 + j * rsk + t * 64, &lA[tid * 8 + j * 2048]);
      gl_lds16(srcB0 + j * rsk + t * 64, &lB[tid * 8 + j * 2048]);
    }
    __syncthreads();
#pragma unroll
    for (int ks = 0; ks < 2; ks++) {
      const int swz = ks ? swz1 : swz0;
      bf16x8 bfr[4], afr[4];
#pragma unroll
      for (int n = 0; n < 4; n++) bfr[n] = *(const bf16x8*)&lB[bRow + n * 1024 + swz];
#pragma unroll
      for (int m = 0; m < 4; m++) afr[m] = *(const bf16x8*)&lA[aRow + m * 1024 + swz];
#pragma unroll
      for (int m = 0; m < 4; m++)
#pragma unroll
        for (int n = 0; n < 4; n++)
          acc[m][n] = __builtin_amdgcn_mfma_f32_16x16x32_bf16(
              afr[m], bfr[n], acc[m][n], 0, 0, 0);
    }
    __syncthreads();
  }

  const int rq = (l >> 4) * 4;
#pragma unroll
  for (int m = 0; m < 4; m++) {
    const int lrow = wy * 64 + m * 16 + rq;
    const int grow = m0 + lrow;
#pragma unroll
    for (int n = 0; n < 4; n++) {
      const int col = n0 + wx * 64 + n * 16 + fr;
#pragma unroll
      for (int r = 0; r < 4; r++)
        Cout[(size_t)bzi * Cb_str + (size_t)(grow + r) * N + col] =
            acc[m][n][r] * rz_lds[lrow + r];
    }
  }
}

// B=8, L=2048, D=512, Y=8192
extern "C" void kernel_launch(void* const* d_in, const int* in_sizes, int n_in,
                              void* d_out, int out_size, void* d_ws, size_t ws_size,
                              hipStream_t stream) {
  const float* x = (const float*)d_in[0];   // [8][2048][512]
  const float* U = (const float*)d_in[1];   // [8192][512]
  if (n_in >= 2 && in_sizes[0] == 8192 * 512) {
    x = (const float*)d_in[1];
    U = (const float*)d_in[0];
  }
  float* out = (float*)d_out;               // [8][8192][512]
  char* ws = (char*)d_ws;

  // ws layout (bytes)
  u16* Ub = (u16*)ws;                       // 8 MiB
  u16* Xb = (u16*)(ws + 8388608);           // 16 MiB
  u16* XT = (u16*)(ws + 25165824);          // 16 MiB
  u16* P  = (u16*)(ws + 41943040);          // all-batch: 256 MiB
  const size_t need_all = 41943040ull + 268435456ull + 262144ull;

  cvt_bf16<<<4096, 256, 0, stream>>>(U, Ub, (8192 * 512) / 4);
  prep_x<<<dim3(16, 64, 8), 256, 0, stream>>>(x, Xb, XT);

  if (ws_size >= need_all) {
    float* z = (float*)(ws + 41943040 + 268435456);
    zero_f32<<<256, 256, 0, stream>>>(z, 8 * 8192);
    // P[b] = exp(U @ x_b^T), fused rowsum -> z[b]; persistent over batches
    gemm1p<<<dim3(16, 64), 256, 0, stream>>>(
        Ub, Xb, P, z, 8, (size_t)2048 * 512, (size_t)8192 * 2048, 16, 64);
    // out[b] = (P[b] @ XT_b^T) / z[b]: M=8192, N=512, K=2048
    gemm2k<<<dim3(4, 64, 8), 256, 0, stream>>>(
        P, XT, out, z, 2048, 32, 512,
        (size_t)8192 * 2048, (size_t)512 * 2048, (size_t)8192 * 512, 4, 64);
  } else {
    // fallback: per-batch P (32 MiB)
    float* z = (float*)(ws + 41943040 + 33554432);
    zero_f32<<<256, 256, 0, stream>>>(z, 8 * 8192);
    for (int b = 0; b < 8; b++) {
      gemm1p<<<dim3(16, 64), 256, 0, stream>>>(
          Ub, Xb + (size_t)b * 2048 * 512, P, z + b * 8192, 1, 0, 0, 16, 64);
      gemm2k<<<dim3(4, 64, 1), 256, 0, stream>>>(
          P, XT + (size_t)b * 512 * 2048, out + (size_t)b * 8192 * 512,
          z + b * 8192, 2048, 32, 512, 0, 0, 0, 4, 64);
    }
  }
}

// Round 12
// 356.820 us; speedup vs baseline: 3.0763x; 1.3265x over previous
//
#include <hip/hip_runtime.h>

typedef unsigned short u16;
typedef unsigned int u32;
typedef __attribute__((ext_vector_type(8))) short bf16x8;
typedef __attribute__((ext_vector_type(4))) float f32x4;

__device__ __forceinline__ u16 f2bf(float f) {
  u32 u = __float_as_uint(f);
  u32 r = (u + 0x7FFFu + ((u >> 16) & 1u)) >> 16;  // RTNE
  return (u16)r;
}

__device__ __forceinline__ void gl_lds16(const u16* g, u16* l) {
  __builtin_amdgcn_global_load_lds(
      (const __attribute__((address_space(1))) u32*)g,
      (__attribute__((address_space(3))) u32*)l, 16, 0, 0);
}

// ---------------- prep: U fp32 -> bf16 ----------------
__global__ __launch_bounds__(256) void cvt_bf16(const float* __restrict__ src,
                                                u16* __restrict__ dst, int n4) {
  int g = blockIdx.x * 256 + threadIdx.x;
  if (g < n4) {
    float4 v = ((const float4*)src)[g];
    ushort4 o;
    o.x = f2bf(v.x); o.y = f2bf(v.y); o.z = f2bf(v.z); o.w = f2bf(v.w);
    ((ushort4*)dst)[g] = o;
  }
}

// ---------------- prep: x fp32 -> Xb bf16 [b][l][d] and XT bf16 [b][d][l] ----------------
__global__ __launch_bounds__(256) void prep_x(const float* __restrict__ x,
                                              u16* __restrict__ Xb,
                                              u16* __restrict__ XT) {
  __shared__ u16 t[32][33];
  const int b = blockIdx.z;
  const int l0 = blockIdx.y * 32;
  const int d0 = blockIdx.x * 32;
  const int j = threadIdx.x & 31;
  const int t5 = threadIdx.x >> 5;
#pragma unroll
  for (int r = 0; r < 4; r++) {
    int i = r * 8 + t5;
    float v = x[((size_t)b * 2048 + l0 + i) * 512 + d0 + j];
    u16 h = f2bf(v);
    t[i][j] = h;
    Xb[((size_t)b * 2048 + l0 + i) * 512 + d0 + j] = h;
  }
  __syncthreads();
#pragma unroll
  for (int r = 0; r < 4; r++) {
    int i = r * 8 + t5;
    XT[((size_t)b * 512 + d0 + i) * 2048 + l0 + j] = t[j][i];
  }
}

// ---------------- gemm1: P[b] = bf16(exp(U @ x_b^T)) ----------------
// R7-exact main loop: 128x128 tile, BK=64, 4 waves 2x2, single-buffered
// swizzled LDS (byte ^= (row&7)<<4), 2-barrier K-loop, 4 blocks/CU.
// NEW epilogue: exp+f2bf into the (dead) LDS buffer as a 128x128 u16 tile,
// then 8 fully-coalesced dwordx4 stores/thread (full 256B line segments,
// no partial-line RMW). No rowsum here (gemm2 derives z itself).
__global__ __launch_bounds__(256, 4)
void gemm1k(const u16* __restrict__ A, const u16* __restrict__ B,
            u16* __restrict__ P, int nt,
            size_t Bb_str, size_t Cb_str, int gx, int gy) {
  __shared__ u16 lds[16384];   // A tile @0, B tile @8192; epilogue: 128x128 u16

  const int nwg = gx * gy * gridDim.z;
  const int orig = blockIdx.x + gx * (blockIdx.y + gy * blockIdx.z);
  const int cpx = nwg >> 3;
  const int nid = (orig & 7) * cpx + (orig >> 3);
  const int bxi = nid % gx;
  const int byi = (nid / gx) % gy;
  const int bzi = nid / (gx * gy);
  const int m0 = byi * 128, n0 = bxi * 128;

  const int tid = threadIdx.x;
  const int l = tid & 63;
  const int w = tid >> 6;
  const int wy = w >> 1, wx = w & 1;

  // staging (write side; inverse-swizzled global source)
  const int rowS = tid >> 3;
  const int cS = ((tid & 7) << 4) ^ ((rowS & 7) << 4);
  const u16* srcA0 = A + (size_t)(m0 + rowS) * 512 + (cS >> 1);
  const u16* srcB0 = B + (size_t)bzi * Bb_str + (size_t)(n0 + rowS) * 512 + (cS >> 1);
  const size_t rsk = (size_t)32 * 512;

  // read side (swizzled ds_read addresses)
  const int fr = l & 15;
  const int X = (fr & 7) << 4;
  const int kb = (l >> 4) << 4;
  const int swz0 = (kb ^ X) >> 1;
  const int swz1 = ((64 + kb) ^ X) >> 1;
  const int aRow = (wy * 64 + fr) * 64;
  const int bRow = (wx * 64 + fr) * 64;

  f32x4 acc[4][4] = {};

  for (int t = 0; t < nt; ++t) {
#pragma unroll
    for (int j = 0; j < 4; j++) {
      gl_lds16(srcA0 + j * rsk + t * 64, &lds[tid * 8 + j * 2048]);
      gl_lds16(srcB0 + j * rsk + t * 64, &lds[8192 + tid * 8 + j * 2048]);
    }
    __syncthreads();
#pragma unroll
    for (int ks = 0; ks < 2; ks++) {
      const int swz = ks ? swz1 : swz0;
      bf16x8 bfr[4], afr[4];
#pragma unroll
      for (int n = 0; n < 4; n++) bfr[n] = *(const bf16x8*)&lds[8192 + bRow + n * 1024 + swz];
#pragma unroll
      for (int m = 0; m < 4; m++) afr[m] = *(const bf16x8*)&lds[aRow + m * 1024 + swz];
#pragma unroll
      for (int m = 0; m < 4; m++)
#pragma unroll
        for (int n = 0; n < 4; n++)
          acc[m][n] = __builtin_amdgcn_mfma_f32_16x16x32_bf16(
              afr[m], bfr[n], acc[m][n], 0, 0, 0);
    }
    __syncthreads();
  }

  // ---- epilogue: exp -> bf16 -> LDS (tile transpose-gather) -> coalesced stores ----
  const int rq = (l >> 4) * 4;  // C/D: col=lane&15, row=(lane>>4)*4+reg
#pragma unroll
  for (int m = 0; m < 4; m++) {
    const int lr0 = wy * 64 + m * 16 + rq;
#pragma unroll
    for (int n = 0; n < 4; n++) {
      const int lc = wx * 64 + n * 16 + fr;
#pragma unroll
      for (int r = 0; r < 4; r++)
        lds[(lr0 + r) * 128 + lc] = f2bf(__expf(acc[m][n][r]));
    }
  }
  __syncthreads();
  u16* Pb = P + (size_t)bzi * Cb_str;
#pragma unroll
  for (int k = 0; k < 8; k++) {
    const int row = k * 16 + (tid >> 4);
    const int cu = (tid & 15) * 8;
    *(uint4*)&Pb[(size_t)(m0 + row) * 2048 + n0 + cu] = *(const uint4*)&lds[row * 128 + cu];
  }
}

// ---------------- gemm2: out[b] = (P[b] @ XT_b^T) / z[b], z from ones-MFMA ----------------
// R7-exact main loop + one extra MFMA per (m,ks) with B=ones: acc_z[m] holds
// rowsum(P) in exactly the C/D lane layout of acc[m][n] -> divide is lane-local.
__global__ __launch_bounds__(256, 4)
void gemm2k(const u16* __restrict__ A, const u16* __restrict__ B,
            float* __restrict__ Cout, int Kstride, int nt, int N,
            size_t Ab_str, size_t Bb_str, size_t Cb_str, int gx, int gy) {
  __shared__ u16 lds[16384];

  const int nwg = gx * gy * gridDim.z;
  const int orig = blockIdx.x + gx * (blockIdx.y + gy * blockIdx.z);
  const int cpx = nwg >> 3;
  const int nid = (orig & 7) * cpx + (orig >> 3);
  const int bxi = nid % gx;
  const int byi = (nid / gx) % gy;
  const int bzi = nid / (gx * gy);
  const int m0 = byi * 128, n0 = bxi * 128;

  const u16* Ab = A + (size_t)bzi * Ab_str;
  const u16* Bb = B + (size_t)bzi * Bb_str;

  const int tid = threadIdx.x;
  const int l = tid & 63;
  const int w = tid >> 6;
  const int wy = w >> 1, wx = w & 1;

  const int rowS = tid >> 3;
  const int cS = ((tid & 7) << 4) ^ ((rowS & 7) << 4);
  const u16* srcA0 = Ab + (size_t)(m0 + rowS) * Kstride + (cS >> 1);
  const u16* srcB0 = Bb + (size_t)(n0 + rowS) * Kstride + (cS >> 1);
  const size_t rsk = (size_t)32 * Kstride;

  const int fr = l & 15;
  const int X = (fr & 7) << 4;
  const int kb = (l >> 4) << 4;
  const int swz0 = (kb ^ X) >> 1;
  const int swz1 = ((64 + kb) ^ X) >> 1;
  const int aRow = (wy * 64 + fr) * 64;
  const int bRow = (wx * 64 + fr) * 64;

  bf16x8 onev;
#pragma unroll
  for (int i = 0; i < 8; i++) onev[i] = (short)0x3F80;  // bf16 1.0

  f32x4 acc[4][4] = {};
  f32x4 accz[4] = {};

  for (int t = 0; t < nt; ++t) {
#pragma unroll
    for (int j = 0; j < 4; j++) {
      gl_lds16(srcA0 + j * rsk + t * 64, &lds[tid * 8 + j * 2048]);
      gl_lds16(srcB0 + j * rsk + t * 64, &lds[8192 + tid * 8 + j * 2048]);
    }
    __syncthreads();
#pragma unroll
    for (int ks = 0; ks < 2; ks++) {
      const int swz = ks ? swz1 : swz0;
      bf16x8 bfr[4], afr[4];
#pragma unroll
      for (int n = 0; n < 4; n++) bfr[n] = *(const bf16x8*)&lds[8192 + bRow + n * 1024 + swz];
#pragma unroll
      for (int m = 0; m < 4; m++) afr[m] = *(const bf16x8*)&lds[aRow + m * 1024 + swz];
#pragma unroll
      for (int m = 0; m < 4; m++) {
        accz[m] = __builtin_amdgcn_mfma_f32_16x16x32_bf16(afr[m], onev, accz[m], 0, 0, 0);
#pragma unroll
        for (int n = 0; n < 4; n++)
          acc[m][n] = __builtin_amdgcn_mfma_f32_16x16x32_bf16(
              afr[m], bfr[n], acc[m][n], 0, 0, 0);
      }
    }
    __syncthreads();
  }

  const int rq = (l >> 4) * 4;
#pragma unroll
  for (int m = 0; m < 4; m++) {
    const int grow = m0 + wy * 64 + m * 16 + rq;
    float iz[4];
#pragma unroll
    for (int r = 0; r < 4; r++) iz[r] = 1.f / accz[m][r];
#pragma unroll
    for (int n = 0; n < 4; n++) {
      const int col = n0 + wx * 64 + n * 16 + fr;
#pragma unroll
      for (int r = 0; r < 4; r++)
        Cout[(size_t)bzi * Cb_str + (size_t)(grow + r) * N + col] =
            acc[m][n][r] * iz[r];
    }
  }
}

// B=8, L=2048, D=512, Y=8192
extern "C" void kernel_launch(void* const* d_in, const int* in_sizes, int n_in,
                              void* d_out, int out_size, void* d_ws, size_t ws_size,
                              hipStream_t stream) {
  const float* x = (const float*)d_in[0];   // [8][2048][512]
  const float* U = (const float*)d_in[1];   // [8192][512]
  if (n_in >= 2 && in_sizes[0] == 8192 * 512) {
    x = (const float*)d_in[1];
    U = (const float*)d_in[0];
  }
  float* out = (float*)d_out;               // [8][8192][512]
  char* ws = (char*)d_ws;

  // ws layout (bytes)
  u16* Ub = (u16*)ws;                       // 8 MiB
  u16* Xb = (u16*)(ws + 8388608);           // 16 MiB
  u16* XT = (u16*)(ws + 25165824);          // 16 MiB
  u16* P  = (u16*)(ws + 41943040);          // all-batch: 256 MiB
  const size_t need_all = 41943040ull + 268435456ull;

  cvt_bf16<<<4096, 256, 0, stream>>>(U, Ub, (8192 * 512) / 4);
  prep_x<<<dim3(16, 64, 8), 256, 0, stream>>>(x, Xb, XT);

  if (ws_size >= need_all) {
    // P[b] = exp(U @ x_b^T): M=8192, N=2048, K=512
    gemm1k<<<dim3(16, 64, 8), 256, 0, stream>>>(
        Ub, Xb, P, 8, (size_t)2048 * 512, (size_t)8192 * 2048, 16, 64);
    // out[b] = (P[b] @ XT_b^T) / rowsum(P[b]): M=8192, N=512, K=2048
    gemm2k<<<dim3(4, 64, 8), 256, 0, stream>>>(
        P, XT, out, 2048, 32, 512,
        (size_t)8192 * 2048, (size_t)512 * 2048, (size_t)8192 * 512, 4, 64);
  } else {
    // fallback: per-batch P (32 MiB)
    for (int b = 0; b < 8; b++) {
      gemm1k<<<dim3(16, 64, 1), 256, 0, stream>>>(
          Ub, Xb + (size_t)b * 2048 * 512, P, 8, 0, 0, 16, 64);
      gemm2k<<<dim3(4, 64, 1), 256, 0, stream>>>(
          P, XT + (size_t)b * 512 * 2048, out + (size_t)b * 8192 * 512,
          2048, 32, 512, 0, 0, 0, 4, 64);
    }
  }
}